// Round 5
// baseline (477.107 us; speedup 1.0000x reference)
//
#include <hip/hip_runtime.h>
#include <hip/hip_bf16.h>
#include <cstdint>
#include <cstddef>

// ActorHead fused pipeline, bf16 MFMA throughout.
//   K1 k_qkv : [4096x1536x512] GEMM-BT, barrier-free direct-global frags -> Qb, Kb, Vt
//   K2 k_attn: split-K flash attention, S^T ordering (A=K, B=Q) so P stays in registers
//              (C-layout of S^T == A-layout of 16x16x16 PV MFMA). No LDS, no barriers.
//              mask/weight read directly (k_bias eliminated); e=exp(sel), masked->0 exact.
//   K2b k_comb: merge splits, influence, valid
//   K3 k_fold: fold out_w over heads; K4 k_out: [4096x128x512] GEMM, direct frags
// d_out = topic[4096*128] fp32 ++ influence[4096] fp32

typedef __attribute__((ext_vector_type(8))) short bf16x8;
typedef __attribute__((ext_vector_type(4))) short bf16x4;
typedef __attribute__((ext_vector_type(4))) float f32x4;

#define MFMA32(a, b, c) __builtin_amdgcn_mfma_f32_16x16x32_bf16((a), (b), (c), 0, 0, 0)
// K=16 bf16 MFMA: the only clang spelling is the gfx90a-era "_1k" builtin; it maps to
// v_mfma_f32_16x16x16_bf16 which gfx950 retains (cdna4_isa.md §10). Do NOT guard with
// __has_builtin — it returns false for aux-target builtins in the HIP host pass.
#define MFMA16(a, b, c) __builtin_amdgcn_mfma_f32_16x16x16bf16_1k((a), (b), (c), 0, 0, 0)

static __device__ __forceinline__ short f2b(float x) {
  union { float f; unsigned u; } v; v.f = x;
  unsigned r = v.u + 0x7fffu + ((v.u >> 16) & 1u);  // RNE to bf16
  return (short)(r >> 16);
}

static __device__ __forceinline__ bf16x8 cvt8(f32x4 lo, f32x4 hi) {
  bf16x8 o;
  o[0] = f2b(lo.x); o[1] = f2b(lo.y); o[2] = f2b(lo.z); o[3] = f2b(lo.w);
  o[4] = f2b(hi.x); o[5] = f2b(hi.y); o[6] = f2b(hi.z); o[7] = f2b(hi.w);
  return o;
}

// ---------------- K1: QKV projection (barrier-free, direct-global frags) ----------------
// grid 768 = 24 col-blocks(64) x 32 row-blocks(128). wave = 64 rows x 32 cols.
__global__ __launch_bounds__(256) void k_qkv(
    const float* __restrict__ a, const float* __restrict__ kv,
    const float* __restrict__ w, const float* __restrict__ bias,
    short* __restrict__ Qb, short* __restrict__ Kb, short* __restrict__ Vt)
{
  const int blk = blockIdx.x;
  const int bm = blk % 32, bn = blk / 32;  // consecutive blocks share the w-slice (L2)
  const int m0 = bm * 128, n0 = bn * 64;
  const float* __restrict__ Ain = (bn < 8) ? a : kv;
  const int tid = threadIdx.x;
  const int lane = tid & 63, wv = tid >> 6;
  const int wm = (wv >> 1) * 64, wn = (wv & 1) * 32;
  const int c = lane & 15, g = lane >> 4;

  f32x4 acc[4][2];
#pragma unroll
  for (int i = 0; i < 4; ++i)
#pragma unroll
    for (int j = 0; j < 2; ++j) acc[i][j] = (f32x4)0.f;

  for (int k0 = 0; k0 < 512; k0 += 32) {
    bf16x8 af[4], bfr[2];
#pragma unroll
    for (int at = 0; at < 4; ++at) {
      const float* p = Ain + (size_t)(m0 + wm + at * 16 + c) * 512 + k0 + g * 8;
      af[at] = cvt8(*(const f32x4*)p, *(const f32x4*)(p + 4));
    }
#pragma unroll
    for (int bt = 0; bt < 2; ++bt) {
      const float* p = w + (size_t)(n0 + wn + bt * 16 + c) * 512 + k0 + g * 8;
      bfr[bt] = cvt8(*(const f32x4*)p, *(const f32x4*)(p + 4));
    }
#pragma unroll
    for (int at = 0; at < 4; ++at)
#pragma unroll
      for (int bt = 0; bt < 2; ++bt)
        acc[at][bt] = MFMA32(af[at], bfr[bt], acc[at][bt]);
  }

#pragma unroll
  for (int bt = 0; bt < 2; ++bt) {
    const int col = n0 + wn + bt * 16 + c;
    const float bj = bias[col];
#pragma unroll
    for (int at = 0; at < 4; ++at) {
      const int row = m0 + wm + at * 16 + g * 4;
      if (col < 512) {
#pragma unroll
        for (int r = 0; r < 4; ++r)
          Qb[(size_t)(row + r) * 512 + col] = f2b((acc[at][bt][r] + bj) * 0.08838834764831843f);
      } else if (col < 1024) {
#pragma unroll
        for (int r = 0; r < 4; ++r)
          Kb[(size_t)(row + r) * 512 + (col - 512)] = f2b(acc[at][bt][r] + bj);
      } else {
        bf16x4 pk;
#pragma unroll
        for (int r = 0; r < 4; ++r) pk[r] = f2b(acc[at][bt][r] + bj);
        *(bf16x4*)(&Vt[(size_t)(col - 1024) * 4096 + row]) = pk;
      }
    }
  }
}

// ---------------- K2: split-K flash attention (S^T ordering, LDS-free, barrier-free) ----
// wg = 32 rows x split. wave = head. Per tile (64 keys): load mask/wgt+K+V (independent),
// S^T = K @ Q^T (C-layout: n=c, m=g*4+r), p=exp(s)*exp(sel) in regs, PV via 16x16x16.
__global__ __launch_bounds__(256) void k_attn(
    const short* __restrict__ Qb, const short* __restrict__ Kb,
    const short* __restrict__ Vt, const float* __restrict__ wgt,
    const int* __restrict__ msk, const int S,
    short* __restrict__ Opart, float* __restrict__ lpart,
    float* __restrict__ cipart, float* __restrict__ lbpart)
{
  const int bx = blockIdx.x;
  const int rb = bx & 127, sp = bx >> 7;  // consecutive blocks share K/V slice (L2)
  const int n0 = rb * 32;
  const int mlen = 4096 / S;
  const int mbase = sp * mlen;
  const int ntiles = mlen >> 6;
  const int tid = threadIdx.x;
  const int lane = tid & 63, h = tid >> 6;
  const int c = lane & 15, g = lane >> 4;

  // Q B-frags (col=n=c, k=g*8+j)
  bf16x8 qf[2][4];
#pragma unroll
  for (int nb = 0; nb < 2; ++nb)
#pragma unroll
    for (int ks = 0; ks < 4; ++ks)
      qf[nb][ks] = *(const bf16x8*)(Qb + (size_t)(n0 + nb * 16 + c) * 512 + h * 128 + ks * 32 + g * 8);

  f32x4 O[2][8];
#pragma unroll
  for (int nb = 0; nb < 2; ++nb)
#pragma unroll
    for (int db = 0; db < 8; ++db) O[nb][db] = (f32x4)0.f;

  float lh[2] = {0.f, 0.f}, lb[2] = {0.f, 0.f}, ci[2] = {0.f, 0.f};

  for (int it = 0; it < ntiles; ++it) {
    const int m0 = mbase + it * 64;

    // ---- mask/wgt loads (independent, issued ahead of MFMA block) ----
    f32x4 ebs[2][4];
#pragma unroll
    for (int nb = 0; nb < 2; ++nb)
#pragma unroll
      for (int mt = 0; mt < 4; ++mt) {
        const size_t idx = (size_t)(n0 + nb * 16 + c) * 4096 + m0 + mt * 16 + g * 4;
        const int4 mk = *(const int4*)(msk + idx);
        const f32x4 wv = *(const f32x4*)(wgt + idx);
        f32x4 s;
        s.x = mk.x ? wv.x : -1e30f;
        s.y = mk.y ? wv.y : -1e30f;
        s.z = mk.z ? wv.z : -1e30f;
        s.w = mk.w ? wv.w : -1e30f;
        ebs[nb][mt] = s;
      }

    // ---- S^T = K @ Q^T, then exp + PV per mt ----
#pragma unroll
    for (int mt = 0; mt < 4; ++mt) {
      bf16x8 kf[4];
#pragma unroll
      for (int ks = 0; ks < 4; ++ks)
        kf[ks] = *(const bf16x8*)(Kb + (size_t)(m0 + mt * 16 + c) * 512 + h * 128 + ks * 32 + g * 8);
      f32x4 Sv[2];
      Sv[0] = (f32x4)0.f; Sv[1] = (f32x4)0.f;
#pragma unroll
      for (int ks = 0; ks < 4; ++ks) {
        Sv[0] = MFMA32(kf[ks], qf[0][ks], Sv[0]);
        Sv[1] = MFMA32(kf[ks], qf[1][ks], Sv[1]);
      }
      // p = exp(qk)*exp(sel); all 4 regs belong to row n=nb*16+c
      bf16x4 pa[2];
#pragma unroll
      for (int nb = 0; nb < 2; ++nb) {
        const f32x4 sel = ebs[nb][mt];
        float e0 = __expf(sel.x), e1 = __expf(sel.y), e2 = __expf(sel.z), e3 = __expf(sel.w);
        float p0 = __expf(Sv[nb][0]) * e0, p1 = __expf(Sv[nb][1]) * e1;
        float p2 = __expf(Sv[nb][2]) * e2, p3 = __expf(Sv[nb][3]) * e3;
        lh[nb] += (p0 + p1) + (p2 + p3);
        lb[nb] += (e0 + e1) + (e2 + e3);
        ci[nb] += (p0 * e0 + p1 * e1) + (p2 * e2 + p3 * e3);
        pa[nb][0] = f2b(p0); pa[nb][1] = f2b(p1); pa[nb][2] = f2b(p2); pa[nb][3] = f2b(p3);
      }
      // PV over this 16-key chunk: A=pa (K=16 frag), B=V frag
#pragma unroll
      for (int db = 0; db < 8; ++db) {
        const bf16x4 vf = *(const bf16x4*)(Vt + (size_t)(h * 128 + db * 16 + c) * 4096 + m0 + mt * 16 + g * 4);
        O[0][db] = MFMA16(pa[0], vf, O[0][db]);
        O[1][db] = MFMA16(pa[1], vf, O[1][db]);
      }
    }
  }

  // ---- reduce over g-groups (lanes ^16, ^32 hold same n=c) ----
#pragma unroll
  for (int nb = 0; nb < 2; ++nb) {
    lh[nb] += __shfl_xor(lh[nb], 16, 64); lh[nb] += __shfl_xor(lh[nb], 32, 64);
    lb[nb] += __shfl_xor(lb[nb], 16, 64); lb[nb] += __shfl_xor(lb[nb], 32, 64);
    ci[nb] += __shfl_xor(ci[nb], 16, 64); ci[nb] += __shfl_xor(ci[nb], 32, 64);
  }

  // ---- normalized O partial: O rows are n=nb*16+g*4+r, lh indexed by c -> shuffle ----
#pragma unroll
  for (int nb = 0; nb < 2; ++nb) {
    float inv[4];
#pragma unroll
    for (int r = 0; r < 4; ++r) {
      const float lhn = __shfl(lh[nb], 4 * g + r, 64);
      inv[r] = 1.f / fmaxf(lhn, 1e-30f);
    }
#pragma unroll
    for (int db = 0; db < 8; ++db)
#pragma unroll
      for (int r = 0; r < 4; ++r)
        Opart[(size_t)sp * (4096 * 512) + (size_t)(n0 + nb * 16 + g * 4 + r) * 512 +
              h * 128 + db * 16 + c] = f2b(O[nb][db][r] * inv[r]);
  }

  if (g == 0) {
#pragma unroll
    for (int nb = 0; nb < 2; ++nb) {
      const int row = n0 + nb * 16 + c;
      lpart[((size_t)sp * 4 + h) * 4096 + row] = lh[nb];
      cipart[((size_t)sp * 4 + h) * 4096 + row] = ci[nb];
      if (h == 0) lbpart[(size_t)sp * 4096 + row] = lb[nb];
    }
  }
}

// ---------------- K2b: combine splits ----------------
__global__ __launch_bounds__(256) void k_comb(
    const short* __restrict__ Opart, const float* __restrict__ lpart,
    const float* __restrict__ cipart, const float* __restrict__ lbpart,
    const int S, short* __restrict__ ctxb, float* __restrict__ validw,
    float* __restrict__ infl)
{
  const int tid = threadIdx.x;
  const int rloc = tid >> 5, cseg = tid & 31;
  const int row = blockIdx.x * 8 + rloc;
  const int col0 = cseg * 16;
  const int h = col0 >> 7;

  float l[4], ciS[4], lb = 0.f;
#pragma unroll
  for (int hh = 0; hh < 4; ++hh) { l[hh] = 0.f; ciS[hh] = 0.f; }
  for (int s = 0; s < S; ++s) {
#pragma unroll
    for (int hh = 0; hh < 4; ++hh) {
      l[hh]   += lpart[((size_t)s * 4 + hh) * 4096 + row];
      ciS[hh] += cipart[((size_t)s * 4 + hh) * 4096 + row];
    }
    lb += lbpart[(size_t)s * 4096 + row];
  }

  float acc[16];
#pragma unroll
  for (int j = 0; j < 16; ++j) acc[j] = 0.f;
  const float linv = 1.f / fmaxf(l[h], 1e-30f);
  for (int s = 0; s < S; ++s) {
    const float w_s = lpart[((size_t)s * 4 + h) * 4096 + row] * linv;
    const bf16x8 o0 = *(const bf16x8*)(Opart + (size_t)s * (4096 * 512) + (size_t)row * 512 + col0);
    const bf16x8 o1 = *(const bf16x8*)(Opart + (size_t)s * (4096 * 512) + (size_t)row * 512 + col0 + 8);
#pragma unroll
    for (int j = 0; j < 8; ++j) {
      union { unsigned u; float f; } v0, v1;
      v0.u = ((unsigned)(unsigned short)o0[j]) << 16;
      v1.u = ((unsigned)(unsigned short)o1[j]) << 16;
      acc[j]     += w_s * v0.f;
      acc[8 + j] += w_s * v1.f;
    }
  }
  bf16x8 c0, c1;
#pragma unroll
  for (int j = 0; j < 8; ++j) { c0[j] = f2b(acc[j]); c1[j] = f2b(acc[8 + j]); }
  *(bf16x8*)(ctxb + (size_t)row * 512 + col0) = c0;
  *(bf16x8*)(ctxb + (size_t)row * 512 + col0 + 8) = c1;

  if (cseg == 0) {
    validw[row] = (lb > 0.f) ? 1.f : 0.f;
    float s_ = 0.f;
#pragma unroll
    for (int hh = 0; hh < 4; ++hh) s_ += ciS[hh] / fmaxf(l[hh], 1e-30f);
    infl[row] = (lb > 0.f) ? s_ / (4.f * lb) : 0.f;
  }
}

// ---------------- K3: fold out_w over heads ----------------
__global__ void k_fold(const float* __restrict__ ow, const float* __restrict__ ob,
                       short* __restrict__ Wf, float* __restrict__ bfo)
{
  const int idx = blockIdx.x * 256 + threadIdx.x;
  if (idx < 128 * 512) {
    const int dk = idx >> 9, d = idx & 511;
    const float s = 0.25f * (ow[(size_t)dk * 512 + d] + ow[(size_t)(dk + 128) * 512 + d] +
                             ow[(size_t)(dk + 256) * 512 + d] + ow[(size_t)(dk + 384) * 512 + d]);
    Wf[(size_t)dk * 512 + d] = f2b(s);
  }
  if (idx < 128) bfo[idx] = 0.25f * (ob[idx] + ob[idx + 128] + ob[idx + 256] + ob[idx + 384]);
}

// ---------------- K4: topic = ctx @ Wfold^T + bfold (direct frags, no LDS) ----------------
// grid 64, wave = 16 rows x 128 cols.
__global__ __launch_bounds__(256) void k_out(
    const short* __restrict__ ctxb, const short* __restrict__ Wf,
    const float* __restrict__ bfo, const float* __restrict__ validw,
    float* __restrict__ topic)
{
  const int tid = threadIdx.x;
  const int lane = tid & 63, wv = tid >> 6;
  const int m0 = blockIdx.x * 64 + wv * 16;
  const int c = lane & 15, g = lane >> 4;

  f32x4 acc[8];
#pragma unroll
  for (int db = 0; db < 8; ++db) acc[db] = (f32x4)0.f;

  for (int k0 = 0; k0 < 512; k0 += 32) {
    const bf16x8 af = *(const bf16x8*)(ctxb + (size_t)(m0 + c) * 512 + k0 + g * 8);
#pragma unroll
    for (int db = 0; db < 8; ++db) {
      const bf16x8 bfr = *(const bf16x8*)(Wf + (size_t)(db * 16 + c) * 512 + k0 + g * 8);
      acc[db] = MFMA32(af, bfr, acc[db]);
    }
  }

#pragma unroll
  for (int r = 0; r < 4; ++r) {
    const int row = m0 + g * 4 + r;
    const float va = validw[row];
#pragma unroll
    for (int db = 0; db < 8; ++db) {
      const int col = db * 16 + c;
      const float vl = (va > 0.5f) ? (acc[db][r] + bfo[col]) : 0.f;
      topic[(size_t)row * 128 + col] = vl;
    }
  }
}

extern "C" void kernel_launch(void* const* d_in, const int* in_sizes, int n_in,
                              void* d_out, int out_size, void* d_ws, size_t ws_size,
                              hipStream_t stream) {
  const float* a_z  = (const float*)d_in[0];
  const float* bv_z = (const float*)d_in[1];
  const int*   mask = (const int*)d_in[2];
  const float* wgt  = (const float*)d_in[3];
  const float* ipw  = (const float*)d_in[4];
  const float* ipb  = (const float*)d_in[5];
  const float* ow   = (const float*)d_in[6];
  const float* ob   = (const float*)d_in[7];
  float* topic = (float*)d_out;              // [4096 x 128]
  float* infl  = (float*)d_out + 4096 * 128; // [4096]

  const size_t MB = (size_t)1 << 20;
  char* ws = (char*)d_ws;
  short* Qb     = (short*)(ws);                    // 4 MB
  short* Kb     = (short*)(ws + 4 * MB);           // 4 MB
  short* Vt     = (short*)(ws + 8 * MB);           // 4 MB  [512][4096]
  short* ctxb   = (short*)(ws + 12 * MB);          // 4 MB
  float* validw = (float*)(ws + 16 * MB);          // 16 KB
  short* Wf     = (short*)(ws + 16 * MB + (64 << 10));   // 128 KB
  float* bfo    = (float*)(ws + 16 * MB + (224 << 10));  // 512 B
  const size_t pbase0 = 16 * MB + (256 << 10);

  // per split: Opart 4MB + lpart 64KB + cipart 64KB + lbpart 16KB
  auto need = [&](int S) { return pbase0 + (size_t)S * (4 * MB + (144 << 10)); };
  int S = 8;
  while (S > 1 && need(S) > ws_size) S >>= 1;

  char* pbase = ws + pbase0;
  short* Opart  = (short*)(pbase);
  float* lpart  = (float*)(pbase + (size_t)S * 4 * MB);
  float* cipart = (float*)(pbase + (size_t)S * 4 * MB + ((size_t)S << 16));
  float* lbpart = (float*)(pbase + (size_t)S * 4 * MB + ((size_t)S << 17));

  k_qkv <<<768, 256, 0, stream>>>(a_z, bv_z, ipw, ipb, Qb, Kb, Vt);
  k_fold<<<256, 256, 0, stream>>>(ow, ob, Wf, bfo);
  k_attn<<<128 * S, 256, 0, stream>>>(Qb, Kb, Vt, wgt, mask, S, Opart, lpart, cipart, lbpart);
  k_comb<<<512, 256, 0, stream>>>(Opart, lpart, cipart, lbpart, S, ctxb, validw, infl);
  k_out <<<64, 256, 0, stream>>>(ctxb, Wf, bfo, validw, topic);
}

// Round 6
// 377.064 us; speedup vs baseline: 1.2653x; 1.2653x over previous
//
#include <hip/hip_runtime.h>
#include <hip/hip_bf16.h>
#include <cstdint>
#include <cstddef>

// ActorHead fused pipeline, bf16 MFMA throughout.
//   K1 k_qkv : LDS-tiled GEMM-BT [4096x1536x512] -> Qb (row-major, scaled),
//              Kp/Vp (MFMA-fragment-order packed: every k_attn load fully coalesced)
//   K2 k_attn: split-K flash attention, S^T ordering (A=K, B=Q), P register-resident,
//              PV via 16x16x16 MFMA. No LDS, no barriers. 16 rows/wg, 4 waves=heads.
//              mask/weight read inline; e=mask?exp(w):0 -> masked contributes exactly 0.
//   K2b k_comb: merge splits, influence, valid
//   K3 k_fold: fold out_w over heads; K4 k_out: [4096x128x512] GEMM, direct frags
// d_out = topic[4096*128] fp32 ++ influence[4096] fp32

typedef __attribute__((ext_vector_type(8))) short bf16x8;
typedef __attribute__((ext_vector_type(4))) short bf16x4;
typedef __attribute__((ext_vector_type(4))) float f32x4;

#define MFMA32(a, b, c) __builtin_amdgcn_mfma_f32_16x16x32_bf16((a), (b), (c), 0, 0, 0)
// K=16 bf16 MFMA: gfx90a-era "_1k" spelling; maps to v_mfma_f32_16x16x16_bf16 (valid gfx950).
#define MFMA16(a, b, c) __builtin_amdgcn_mfma_f32_16x16x16bf16_1k((a), (b), (c), 0, 0, 0)

static __device__ __forceinline__ short f2b(float x) {
  union { float f; unsigned u; } v; v.f = x;
  unsigned r = v.u + 0x7fffu + ((v.u >> 16) & 1u);  // RNE to bf16
  return (short)(r >> 16);
}

// ---------------- K1: QKV projection (LDS-tiled, packed epilogue) ----------------
// Kp[(((h*256+mc)*4+ks)*64 + g*16+cK)*8 + j]  <- K[mc*16+cK][h*128+ks*32+g*8+j]
// Vp[(((h*256+mc)*8+db)*64 + gv*16+cv)*4 + j] <- V[mc*16+gv*4+j][h*128+db*16+cv]
__global__ __launch_bounds__(256) void k_qkv(
    const float* __restrict__ a, const float* __restrict__ kv,
    const float* __restrict__ w, const float* __restrict__ bias,
    short* __restrict__ Qb, short* __restrict__ Kp, short* __restrict__ Vp)
{
  __shared__ short As[128 * 40];
  __shared__ short Bs[128 * 40];
  const int blk = blockIdx.x;
  const int bm = blk / 12, bn = blk % 12;
  const int m0 = bm * 128, n0 = bn * 128;
  const float* __restrict__ Ain = (bn < 4) ? a : kv;
  const int tid = threadIdx.x;
  const int lane = tid & 63, wv = tid >> 6;
  const int wm = (wv >> 1) * 64, wn = (wv & 1) * 64;
  const int c = lane & 15, g = lane >> 4;
  const int srow = tid >> 1, scol = (tid & 1) * 16;

  f32x4 acc[4][4];
#pragma unroll
  for (int i = 0; i < 4; ++i)
#pragma unroll
    for (int j = 0; j < 4; ++j) acc[i][j] = (f32x4)0.f;

  for (int k0 = 0; k0 < 512; k0 += 32) {
    const float* ap = Ain + (size_t)(m0 + srow) * 512 + k0 + scol;
    const float* bp = w + (size_t)(n0 + srow) * 512 + k0 + scol;
#pragma unroll
    for (int j = 0; j < 4; ++j) {
      f32x4 av = *(const f32x4*)(ap + 4 * j);
      f32x4 bv = *(const f32x4*)(bp + 4 * j);
      bf16x4 as, bs;
      as.x = f2b(av.x); as.y = f2b(av.y); as.z = f2b(av.z); as.w = f2b(av.w);
      bs.x = f2b(bv.x); bs.y = f2b(bv.y); bs.z = f2b(bv.z); bs.w = f2b(bv.w);
      *(bf16x4*)(&As[srow * 40 + scol + 4 * j]) = as;
      *(bf16x4*)(&Bs[srow * 40 + scol + 4 * j]) = bs;
    }
    __syncthreads();
    bf16x8 af[4], bfg[4];
#pragma unroll
    for (int t = 0; t < 4; ++t) {
      af[t]  = *(const bf16x8*)(&As[(wm + t * 16 + c) * 40 + g * 8]);
      bfg[t] = *(const bf16x8*)(&Bs[(wn + t * 16 + c) * 40 + g * 8]);
    }
#pragma unroll
    for (int rt = 0; rt < 4; ++rt)
#pragma unroll
      for (int ct = 0; ct < 4; ++ct)
        acc[rt][ct] = MFMA32(af[rt], bfg[ct], acc[rt][ct]);
    __syncthreads();
  }

#pragma unroll
  for (int ct = 0; ct < 4; ++ct) {
    const int col = n0 + wn + ct * 16 + c;
    const float bj = bias[col];
#pragma unroll
    for (int rt = 0; rt < 4; ++rt) {
      const int row = m0 + wm + rt * 16 + g * 4;  // row..row+3; row&15 = g*4
      const int mc = row >> 4;
      if (bn < 4) {
#pragma unroll
        for (int r = 0; r < 4; ++r)
          Qb[(size_t)(row + r) * 512 + col] = f2b((acc[rt][ct][r] + bj) * 0.08838834764831843f);
      } else if (bn < 8) {
        const int colK = col - 512;
        const int h = colK >> 7, dk = colK & 127;
        const int ks = dk >> 5, gk = (dk >> 3) & 3, j = dk & 7;
        short* base = Kp + (size_t)((((h * 256 + mc) * 4 + ks) * 64) + gk * 16 + g * 4) * 8 + j;
#pragma unroll
        for (int r = 0; r < 4; ++r) base[r * 8] = f2b(acc[rt][ct][r] + bj);
      } else {
        const int colV = col - 1024;
        const int h = colV >> 7, db = (colV & 127) >> 4, cv = colV & 15;
        bf16x4 pk;
#pragma unroll
        for (int r = 0; r < 4; ++r) pk[r] = f2b(acc[rt][ct][r] + bj);
        *(bf16x4*)(Vp + (size_t)((((h * 256 + mc) * 8 + db) * 64) + g * 16 + cv) * 4) = pk;
      }
    }
  }
}

// ---------------- K2: split-K flash attention (packed frags, LDS-free, barrier-free) ----
// wg = 16 rows x split; wave = head. Per 16-key chunk: 1 int4 + 1 float4 (mask/wgt),
// 4 coalesced Kp bf16x8, S^T = K@Q^T, p=exp(qk)*e in regs, 8 coalesced Vp bf16x4 PV.
__global__ __launch_bounds__(256, 4) void k_attn(
    const short* __restrict__ Qb, const short* __restrict__ Kp,
    const short* __restrict__ Vp, const float* __restrict__ wgt,
    const int* __restrict__ msk, const int S,
    short* __restrict__ Opart, float* __restrict__ lpart,
    float* __restrict__ cipart, float* __restrict__ lbpart)
{
  const int bx = blockIdx.x;
  const int rb = bx & 255, sp = bx >> 8;
  const int n0 = rb * 16;
  const int mlen = 4096 / S;
  const int mc0 = (sp * mlen) >> 4;
  const int nch = mlen >> 4;
  const int tid = threadIdx.x;
  const int lane = tid & 63, h = tid >> 6;
  const int c = lane & 15, g = lane >> 4;

  // Q B-frags (col=n=c, k=g*8+j), one-time load
  bf16x8 qf[4];
#pragma unroll
  for (int ks = 0; ks < 4; ++ks)
    qf[ks] = *(const bf16x8*)(Qb + (size_t)(n0 + c) * 512 + h * 128 + ks * 32 + g * 8);

  f32x4 O[8];
#pragma unroll
  for (int db = 0; db < 8; ++db) O[db] = (f32x4)0.f;
  float lh = 0.f, lb = 0.f, ci = 0.f;

  const short* Kw = Kp + (size_t)h * 524288 + (size_t)lane * 8;  // + mc*2048 + ks*512
  const short* Vw = Vp + (size_t)h * 524288 + (size_t)lane * 4;  // + mc*2048 + db*256
  const size_t ebase = (size_t)(n0 + c) * 4096 + g * 4;

  for (int t = 0; t < nch; ++t) {
    const int mc = mc0 + t;
    // mask/wgt (the only non-packed loads; mandatory HBM traffic)
    const int4 mk = *(const int4*)(msk + ebase + mc * 16);
    const f32x4 wvv = *(const f32x4*)(wgt + ebase + mc * 16);
    // K frags: fully coalesced
    bf16x8 kf[4];
#pragma unroll
    for (int ks = 0; ks < 4; ++ks)
      kf[ks] = *(const bf16x8*)(Kw + mc * 2048 + ks * 512);
    f32x4 Sv = (f32x4)0.f;
#pragma unroll
    for (int ks = 0; ks < 4; ++ks) Sv = MFMA32(kf[ks], qf[ks], Sv);
    // e = mask ? exp(w) : 0; p = exp(qk) * e  (masked -> exactly 0)
    const float e0 = mk.x ? __expf(wvv.x) : 0.f;
    const float e1 = mk.y ? __expf(wvv.y) : 0.f;
    const float e2 = mk.z ? __expf(wvv.z) : 0.f;
    const float e3 = mk.w ? __expf(wvv.w) : 0.f;
    const float p0 = __expf(Sv[0]) * e0, p1 = __expf(Sv[1]) * e1;
    const float p2 = __expf(Sv[2]) * e2, p3 = __expf(Sv[3]) * e3;
    lh += (p0 + p1) + (p2 + p3);
    lb += (e0 + e1) + (e2 + e3);
    ci += (p0 * e0 + p1 * e1) + (p2 * e2 + p3 * e3);
    bf16x4 pa;
    pa[0] = f2b(p0); pa[1] = f2b(p1); pa[2] = f2b(p2); pa[3] = f2b(p3);
    // PV: fully coalesced V frags
#pragma unroll
    for (int db = 0; db < 8; ++db) {
      const bf16x4 vf = *(const bf16x4*)(Vw + mc * 2048 + db * 256);
      O[db] = MFMA16(pa, vf, O[db]);
    }
  }

  // reduce over g-groups (lanes ^16, ^32 share actor n=c)
  lh += __shfl_xor(lh, 16, 64); lh += __shfl_xor(lh, 32, 64);
  lb += __shfl_xor(lb, 16, 64); lb += __shfl_xor(lb, 32, 64);
  ci += __shfl_xor(ci, 16, 64); ci += __shfl_xor(ci, 32, 64);

  // normalized O partial: O rows are n=4g+r; lh indexed by c -> shuffle
  float inv[4];
#pragma unroll
  for (int r = 0; r < 4; ++r)
    inv[r] = 1.f / fmaxf(__shfl(lh, 4 * g + r, 64), 1e-30f);
#pragma unroll
  for (int db = 0; db < 8; ++db)
#pragma unroll
    for (int r = 0; r < 4; ++r)
      Opart[(size_t)sp * (4096 * 512) + (size_t)(n0 + g * 4 + r) * 512 +
            h * 128 + db * 16 + c] = f2b(O[db][r] * inv[r]);

  if (g == 0) {
    const int row = n0 + c;
    lpart[((size_t)sp * 4 + h) * 4096 + row] = lh;
    cipart[((size_t)sp * 4 + h) * 4096 + row] = ci;
    if (h == 0) lbpart[(size_t)sp * 4096 + row] = lb;
  }
}

// ---------------- K2b: combine splits ----------------
__global__ __launch_bounds__(256) void k_comb(
    const short* __restrict__ Opart, const float* __restrict__ lpart,
    const float* __restrict__ cipart, const float* __restrict__ lbpart,
    const int S, short* __restrict__ ctxb, float* __restrict__ validw,
    float* __restrict__ infl)
{
  const int tid = threadIdx.x;
  const int rloc = tid >> 5, cseg = tid & 31;
  const int row = blockIdx.x * 8 + rloc;
  const int col0 = cseg * 16;
  const int h = col0 >> 7;

  float l[4], ciS[4], lb = 0.f;
#pragma unroll
  for (int hh = 0; hh < 4; ++hh) { l[hh] = 0.f; ciS[hh] = 0.f; }
  for (int s = 0; s < S; ++s) {
#pragma unroll
    for (int hh = 0; hh < 4; ++hh) {
      l[hh]   += lpart[((size_t)s * 4 + hh) * 4096 + row];
      ciS[hh] += cipart[((size_t)s * 4 + hh) * 4096 + row];
    }
    lb += lbpart[(size_t)s * 4096 + row];
  }

  float acc[16];
#pragma unroll
  for (int j = 0; j < 16; ++j) acc[j] = 0.f;
  const float linv = 1.f / fmaxf(l[h], 1e-30f);
  for (int s = 0; s < S; ++s) {
    const float w_s = lpart[((size_t)s * 4 + h) * 4096 + row] * linv;
    const bf16x8 o0 = *(const bf16x8*)(Opart + (size_t)s * (4096 * 512) + (size_t)row * 512 + col0);
    const bf16x8 o1 = *(const bf16x8*)(Opart + (size_t)s * (4096 * 512) + (size_t)row * 512 + col0 + 8);
#pragma unroll
    for (int j = 0; j < 8; ++j) {
      union { unsigned u; float f; } v0, v1;
      v0.u = ((unsigned)(unsigned short)o0[j]) << 16;
      v1.u = ((unsigned)(unsigned short)o1[j]) << 16;
      acc[j]     += w_s * v0.f;
      acc[8 + j] += w_s * v1.f;
    }
  }
  bf16x8 c0, c1;
#pragma unroll
  for (int j = 0; j < 8; ++j) { c0[j] = f2b(acc[j]); c1[j] = f2b(acc[8 + j]); }
  *(bf16x8*)(ctxb + (size_t)row * 512 + col0) = c0;
  *(bf16x8*)(ctxb + (size_t)row * 512 + col0 + 8) = c1;

  if (cseg == 0) {
    validw[row] = (lb > 0.f) ? 1.f : 0.f;
    float s_ = 0.f;
#pragma unroll
    for (int hh = 0; hh < 4; ++hh) s_ += ciS[hh] / fmaxf(l[hh], 1e-30f);
    infl[row] = (lb > 0.f) ? s_ / (4.f * lb) : 0.f;
  }
}

// ---------------- K3: fold out_w over heads ----------------
__global__ void k_fold(const float* __restrict__ ow, const float* __restrict__ ob,
                       short* __restrict__ Wf, float* __restrict__ bfo)
{
  const int idx = blockIdx.x * 256 + threadIdx.x;
  if (idx < 128 * 512) {
    const int dk = idx >> 9, d = idx & 511;
    const float s = 0.25f * (ow[(size_t)dk * 512 + d] + ow[(size_t)(dk + 128) * 512 + d] +
                             ow[(size_t)(dk + 256) * 512 + d] + ow[(size_t)(dk + 384) * 512 + d]);
    Wf[(size_t)dk * 512 + d] = f2b(s);
  }
  if (idx < 128) bfo[idx] = 0.25f * (ob[idx] + ob[idx + 128] + ob[idx + 256] + ob[idx + 384]);
}

// ---------------- K4: topic = ctx @ Wfold^T + bfold (direct frags) ----------------
__global__ __launch_bounds__(256) void k_out(
    const short* __restrict__ ctxb, const short* __restrict__ Wf,
    const float* __restrict__ bfo, const float* __restrict__ validw,
    float* __restrict__ topic)
{
  const int tid = threadIdx.x;
  const int lane = tid & 63, wv = tid >> 6;
  const int m0 = blockIdx.x * 64 + wv * 16;
  const int c = lane & 15, g = lane >> 4;

  f32x4 acc[8];
#pragma unroll
  for (int db = 0; db < 8; ++db) acc[db] = (f32x4)0.f;

  for (int k0 = 0; k0 < 512; k0 += 32) {
    const bf16x8 af = *(const bf16x8*)(ctxb + (size_t)(m0 + c) * 512 + k0 + g * 8);
#pragma unroll
    for (int db = 0; db < 8; ++db) {
      const bf16x8 bfr = *(const bf16x8*)(Wf + (size_t)(db * 16 + c) * 512 + k0 + g * 8);
      acc[db] = MFMA32(af, bfr, acc[db]);
    }
  }

#pragma unroll
  for (int r = 0; r < 4; ++r) {
    const int row = m0 + g * 4 + r;
    const float va = validw[row];
#pragma unroll
    for (int db = 0; db < 8; ++db) {
      const int col = db * 16 + c;
      const float vl = (va > 0.5f) ? (acc[db][r] + bfo[col]) : 0.f;
      topic[(size_t)row * 128 + col] = vl;
    }
  }
}

extern "C" void kernel_launch(void* const* d_in, const int* in_sizes, int n_in,
                              void* d_out, int out_size, void* d_ws, size_t ws_size,
                              hipStream_t stream) {
  const float* a_z  = (const float*)d_in[0];
  const float* bv_z = (const float*)d_in[1];
  const int*   mask = (const int*)d_in[2];
  const float* wgt  = (const float*)d_in[3];
  const float* ipw  = (const float*)d_in[4];
  const float* ipb  = (const float*)d_in[5];
  const float* ow   = (const float*)d_in[6];
  const float* ob   = (const float*)d_in[7];
  float* topic = (float*)d_out;              // [4096 x 128]
  float* infl  = (float*)d_out + 4096 * 128; // [4096]

  const size_t MB = (size_t)1 << 20;
  char* ws = (char*)d_ws;
  short* Qb     = (short*)(ws);                    // 4 MB
  short* Kp     = (short*)(ws + 4 * MB);           // 4 MB packed K frags
  short* Vp     = (short*)(ws + 8 * MB);           // 4 MB packed V frags
  short* ctxb   = (short*)(ws + 12 * MB);          // 4 MB
  float* validw = (float*)(ws + 16 * MB);          // 16 KB
  short* Wf     = (short*)(ws + 16 * MB + (64 << 10));   // 128 KB
  float* bfo    = (float*)(ws + 16 * MB + (224 << 10));  // 512 B
  const size_t pbase0 = 16 * MB + (256 << 10);

  // per split: Opart 4MB + lpart 64KB + cipart 64KB + lbpart 16KB
  auto need = [&](int S) { return pbase0 + (size_t)S * (4 * MB + (144 << 10)); };
  int S = 4;
  while (S > 1 && need(S) > ws_size) S >>= 1;

  char* pbase = ws + pbase0;
  short* Opart  = (short*)(pbase);
  float* lpart  = (float*)(pbase + (size_t)S * 4 * MB);
  float* cipart = (float*)(pbase + (size_t)S * 4 * MB + ((size_t)S << 16));
  float* lbpart = (float*)(pbase + (size_t)S * 4 * MB + ((size_t)S << 17));

  k_qkv <<<384, 256, 0, stream>>>(a_z, bv_z, ipw, ipb, Qb, Kp, Vp);
  k_fold<<<256, 256, 0, stream>>>(ow, ob, Wf, bfo);
  k_attn<<<256 * S, 256, 0, stream>>>(Qb, Kp, Vp, wgt, mask, S, Opart, lpart, cipart, lbpart);
  k_comb<<<512, 256, 0, stream>>>(Opart, lpart, cipart, lbpart, S, ctxb, validw, infl);
  k_out <<<64, 256, 0, stream>>>(ctxb, Wf, bfo, validw, topic);
}